// Round 9
// baseline (310.824 us; speedup 1.0000x reference)
//
#include <hip/hip_runtime.h>
#include <hip/hip_bf16.h>
#include <math.h>

#define N_NODES 50000
#define N_EDGES 1600000
#define IN_DIM  128
#define HID     64
#define EPB     4096   // edges per sort block
#define NBLK    391    // ceil(N_EDGES / EPB)
#define NB      391    // ceil(N_NODES / 128) buckets of 128 nodes
#define CAP     8192   // LDS staging capacity (edges/bucket; mean 4092)
static constexpr float EPS = 1e-6f;

typedef __attribute__((ext_vector_type(8))) short          short8;   // 8 bf16
typedef __attribute__((ext_vector_type(8))) unsigned short ushort8;
typedef __attribute__((ext_vector_type(4))) float          f32x4;

__device__ __forceinline__ float bf2f(unsigned int hi_bits) {   // bits already in [31:16]
    union { unsigned int i; float f; } c; c.i = hi_bits; return c.f;
}
__device__ __forceinline__ unsigned short f2bf(float f) {   // round-nearest-even
    union { float f; unsigned int i; } c; c.f = f;
    unsigned int r = c.i + 0x7FFFu + ((c.i >> 16) & 1u);
    return (unsigned short)(r >> 16);
}
__device__ __forceinline__ unsigned char f2fp8(float f) {   // OCP e4m3, HW cvt
    int p = __builtin_amdgcn_cvt_pk_fp8_f32(f, f, 0, false);
    return (unsigned char)(p & 0xff);
}

// ==== weight packing =========================================================

// pack W[K x 64] fp32 -> bf16 MFMA B-fragment order (one slot per thread)
template <int K>
__device__ __forceinline__ void pack_body(const float* __restrict__ wS,
                                          const float* __restrict__ wN,
                                          unsigned short* __restrict__ pS,
                                          unsigned short* __restrict__ pN, int blk) {
    constexpr int NSLOT = (K / 32) * 4 * 64;
    int slot = blk * 256 + (int)threadIdx.x;
    if (slot >= NSLOT) return;
    int lane = slot & 63;
    int ct   = slot >> 6;
    int t    = ct & 3;
    int c    = ct >> 2;
    int m    = lane & 15;
    int quad = lane >> 4;
    int col  = t * 16 + m;
#pragma unroll
    for (int j = 0; j < 8; ++j) {
        int k = c * 32 + quad * 8 + j;
        pS[slot * 8 + j] = f2bf(wS[k * 64 + col]);
        pN[slot * 8 + j] = f2bf(wN[k * 64 + col]);
    }
}

// ==== CSR build: binned counting sort ========================================

// blocks 0..NBLK-1: per-block bucket histogram; blocks NBLK..NBLK+7: weight pack
__global__ __launch_bounds__(256) void bucket_count_pack(
    const int* __restrict__ ei, int* __restrict__ blockCounts,
    const float* __restrict__ w0s, const float* __restrict__ w0n,
    const float* __restrict__ w1s, const float* __restrict__ w1n,
    const float* __restrict__ w2s, const float* __restrict__ w2n,
    unsigned short* __restrict__ p0S, unsigned short* __restrict__ p0N,
    unsigned short* __restrict__ p1S, unsigned short* __restrict__ p1N,
    unsigned short* __restrict__ p2S, unsigned short* __restrict__ p2N) {
    if (blockIdx.x >= NBLK) {
        int blk = blockIdx.x - NBLK;
        if (blk < 4)      pack_body<IN_DIM>(w0s, w0n, p0S, p0N, blk);
        else if (blk < 6) pack_body<HID>(w1s, w1n, p1S, p1N, blk - 4);
        else              pack_body<HID>(w2s, w2n, p2S, p2N, blk - 6);
        return;
    }
    __shared__ int hist[NB];
    for (int i = threadIdx.x; i < NB; i += 256) hist[i] = 0;
    __syncthreads();
    int base = blockIdx.x * EPB;
    int lim  = min(EPB, N_EDGES - base);
    for (int i = threadIdx.x; i < lim; i += 256)
        atomicAdd(&hist[ei[N_EDGES + base + i] >> 7], 1);
    __syncthreads();
    for (int b = threadIdx.x; b < NB; b += 256)
        blockCounts[blockIdx.x * NB + b] = hist[b];
}

// ==== dual GEMM body (device fn so it can be packed into other dispatches) ===
// hs = A@wS (fp32 out), hn = A@wN (fp8 e4m3 out)
template <int K, bool F32IN>
__device__ __forceinline__ void gemm_body(
    const void* __restrict__ Av,
    const unsigned short* __restrict__ pS,
    const unsigned short* __restrict__ pN,
    float* __restrict__ hs, unsigned char* __restrict__ hnq, int blk) {
    constexpr int NC = K / 32;
    int lane = threadIdx.x & 63;
    int wv   = threadIdx.x >> 6;
    int tile = blk * 4 + wv;
    if (tile >= N_NODES / 16) return;
    int m    = lane & 15;
    int quad = lane >> 4;

    const short8* pSf = (const short8*)pS;
    const short8* pNf = (const short8*)pN;

    f32x4 accS[4], accN[4];
#pragma unroll
    for (int t = 0; t < 4; ++t) {
        accS[t] = (f32x4){0.f, 0.f, 0.f, 0.f};
        accN[t] = (f32x4){0.f, 0.f, 0.f, 0.f};
    }
#pragma unroll
    for (int c = 0; c < NC; ++c) {
        short8 a;
        if constexpr (F32IN) {
            const float* Af = (const float*)Av + ((size_t)tile * 16 + m) * K + quad * 8 + c * 32;
            f32x4 a0 = *(const f32x4*)Af;
            f32x4 a1 = *(const f32x4*)(Af + 4);
#pragma unroll
            for (int k = 0; k < 4; ++k) a[k]     = (short)f2bf(a0[k]);
#pragma unroll
            for (int k = 0; k < 4; ++k) a[k + 4] = (short)f2bf(a1[k]);
        } else {
            const short8* Af = (const short8*)((const unsigned short*)Av +
                               ((size_t)tile * 16 + m) * K + quad * 8);
            a = Af[c * 4];
        }
#pragma unroll
        for (int t = 0; t < 4; ++t) {
            short8 bs = pSf[(c * 4 + t) * 64 + lane];
            short8 bn = pNf[(c * 4 + t) * 64 + lane];
            accS[t] = __builtin_amdgcn_mfma_f32_16x16x32_bf16(a, bs, accS[t], 0, 0, 0);
            accN[t] = __builtin_amdgcn_mfma_f32_16x16x32_bf16(a, bn, accN[t], 0, 0, 0);
        }
    }
    int row0 = tile * 16 + quad * 4;
#pragma unroll
    for (int t = 0; t < 4; ++t) {
#pragma unroll
        for (int r = 0; r < 4; ++r) {
            size_t o = (size_t)(row0 + r) * HID + t * 16 + m;
            hs[o]  = accS[t][r];
            hnq[o] = f2fp8(accN[t][r]);
        }
    }
}

// blocks 0..NB-1: col_sum; blocks NB.. : layer-0 GEMM (independent work overlap)
__global__ __launch_bounds__(256) void col_sum_gemm0(
    const int* __restrict__ blockCounts, int* __restrict__ totals,
    const float* __restrict__ x,
    const unsigned short* __restrict__ p0S, const unsigned short* __restrict__ p0N,
    float* __restrict__ hs, unsigned char* __restrict__ hnq) {
    if (blockIdx.x >= NB) {
        gemm_body<IN_DIM, true>(x, p0S, p0N, hs, hnq, blockIdx.x - NB);
        return;
    }
    __shared__ int ws[4];
    int b = blockIdx.x;
    int s = 0;
    for (int i = threadIdx.x; i < NBLK; i += 256) s += blockCounts[i * NB + b];
#pragma unroll
    for (int off = 32; off >= 1; off >>= 1) s += __shfl_xor(s, off, 64);
    if ((threadIdx.x & 63) == 0) ws[threadIdx.x >> 6] = s;
    __syncthreads();
    if (threadIdx.x == 0) totals[b] = ws[0] + ws[1] + ws[2] + ws[3];
}

// col_fix + integrated base scan: every block computes its own column base from
// totals (no separate base_scan dispatch); also writes bucketBase.
__global__ __launch_bounds__(256) void col_fix_base(int* __restrict__ blockCounts,
                                                    const int* __restrict__ totals,
                                                    int* __restrict__ bucketBase) {
    __shared__ int vals[NBLK];
    __shared__ int sbase;
    int b = blockIdx.x;
    for (int i = threadIdx.x; i < NBLK; i += 256) vals[i] = blockCounts[i * NB + b];
    if (threadIdx.x < 64) {   // wave 0: base_b = sum totals[0..b)
        int lane = threadIdx.x;
        int s = 0;
        for (int i = lane; i < b; i += 64) s += totals[i];
#pragma unroll
        for (int off = 32; off >= 1; off >>= 1) s += __shfl_xor(s, off, 64);
        if (lane == 0) {
            sbase = s;
            bucketBase[b] = s;
            if (b == NB - 1) bucketBase[NB] = s + totals[b];   // == N_EDGES
        }
    }
    __syncthreads();
    if (threadIdx.x < 64) {
        int lane  = threadIdx.x;
        int carry = sbase;
        for (int base = 0; base < NBLK; base += 64) {
            int i = base + lane;
            int v = (i < NBLK) ? vals[i] : 0;
            int incl = v;
#pragma unroll
            for (int off = 1; off < 64; off <<= 1) {
                int t = __shfl_up(incl, off, 64);
                if (lane >= off) incl += t;
            }
            if (i < NBLK) vals[i] = carry + incl - v;
            carry += __shfl(incl, 63, 64);
        }
    }
    __syncthreads();
    for (int i = threadIdx.x; i < NBLK; i += 256) blockCounts[i * NB + b] = vals[i];
}

// scatter edges into bucket-sorted order, packed (src<<7)|(dst&127)
__global__ __launch_bounds__(256) void bucket_scatter(const int* __restrict__ ei,
                                                      const int* __restrict__ blockCounts,
                                                      unsigned int* __restrict__ bucketPacked) {
    __shared__ int cur[NB];
    for (int b = threadIdx.x; b < NB; b += 256)
        cur[b] = blockCounts[blockIdx.x * NB + b];
    __syncthreads();
    int base = blockIdx.x * EPB;
    int lim  = min(EPB, N_EDGES - base);
    for (int i = threadIdx.x; i < lim; i += 256) {
        int s = ei[base + i];
        int d = ei[N_EDGES + base + i];
        int pos = atomicAdd(&cur[d >> 7], 1);
        bucketPacked[pos] = ((unsigned int)s << 7) | (unsigned int)(d & 127);
    }
}

// fused: per-bucket degree count -> in-bucket scan -> rowptr -> local scatter.
__global__ __launch_bounds__(256) void node_scan_scatter(
    const unsigned int* __restrict__ bucketPacked, const int* __restrict__ bucketBase,
    int* __restrict__ rowptr, int* __restrict__ csr_src) {
    __shared__ int cnt[128];
    __shared__ int half0;
    __shared__ unsigned int stage[CAP];
    int tid = threadIdx.x;
    if (tid < 128) cnt[tid] = 0;
    __syncthreads();
    int beg = bucketBase[blockIdx.x], end = bucketBase[blockIdx.x + 1];
    int n = end - beg;
    for (int i = tid; i < n; i += 256) {
        unsigned int e = bucketPacked[beg + i];
        if (i < CAP) stage[i] = e;
        atomicAdd(&cnt[e & 127], 1);
    }
    __syncthreads();
    int lane = tid & 63;
    int v    = (tid < 128) ? cnt[tid] : 0;
    int incl = v;
#pragma unroll
    for (int off = 1; off < 64; off <<= 1) {
        int t = __shfl_up(incl, off, 64);
        if (lane >= off) incl += t;
    }
    if (tid == 63) half0 = incl;
    __syncthreads();
    int base  = beg + ((tid >= 64 && tid < 128) ? half0 : 0);
    int start = base + incl - v;
    int node  = blockIdx.x * 128 + tid;
    if (tid < 128) {
        if (node < N_NODES) rowptr[node] = start;
        cnt[tid] = start;   // becomes the scatter cursor
    }
    if (blockIdx.x == 0 && tid == 128) rowptr[N_NODES] = N_EDGES;
    __syncthreads();
    for (int i = tid; i < n; i += 256) {
        unsigned int e = (i < CAP) ? stage[i] : bucketPacked[beg + i];
        int pos = atomicAdd(&cnt[e & 127], 1);
        csr_src[pos] = (int)(e >> 7);
    }
}

// ==== gemm wrapper (layers 1,2) ==============================================
template <int K, bool F32IN>
__global__ __launch_bounds__(256) void gemm_dual_mfma(
    const void* __restrict__ Av,
    const unsigned short* __restrict__ pS,
    const unsigned short* __restrict__ pN,
    float* __restrict__ hs, unsigned char* __restrict__ hnq) {
    gemm_body<K, F32IN>(Av, pS, pN, hs, hnq, blockIdx.x);
}

// ==== fused gather-aggregate + update (+ optional MLP head) ==================
// Lane = (g,r): g = edge slot 0..15 (16 edges in flight), r = 16B chunk 0..3 of
// the 64B fp8 row. MLP=true (layer 2): apply relu(h@mw1+mb1)@mw2+mb2 -> sigmoid
// and write out[node] directly (h never stored).
template <bool MLP>
__global__ __launch_bounds__(256) void agg_update(
    const int* __restrict__ rowptr, const int* __restrict__ csr_src,
    const unsigned char* __restrict__ hnq, const float* __restrict__ hs,
    unsigned short* __restrict__ hb_out,
    const float* __restrict__ mw1, const float* __restrict__ mb1,
    const float* __restrict__ mw2, const float* __restrict__ mb2,
    float* __restrict__ out) {
    __shared__ float sW1[MLP ? HID * 32 : 1];
    __shared__ float sW2[MLP ? 32 : 1];
    __shared__ float sB1[MLP ? 32 : 1];
    __shared__ float sH[MLP ? 4 * HID : 1];
    if (MLP) {
        for (int i = threadIdx.x; i < HID * 32; i += 256) sW1[i] = mw1[i];
        if (threadIdx.x < 32) { sW2[threadIdx.x] = mw2[threadIdx.x]; sB1[threadIdx.x] = mb1[threadIdx.x]; }
        __syncthreads();
    }
    int node = (blockIdx.x * 256 + threadIdx.x) >> 6;   // grid covers exactly N_NODES
    int lane = threadIdx.x & 63;
    int g = lane >> 2;   // edge slot 0..15
    int r = lane & 3;    // 16B chunk 0..3
    int beg = rowptr[node];
    int end = rowptr[node + 1];
    float acc[16];
#pragma unroll
    for (int k = 0; k < 16; ++k) acc[k] = 0.f;
    for (int e = beg; e < end; e += 64) {
        int cnt = min(64, end - e);
        int idx = (lane < cnt) ? csr_src[e + lane] : 0;
        for (int j = 0; j < cnt; j += 16) {
            int s = __shfl(idx, j + g, 64);
            if (j + g < cnt) {
                uint4 w = *(const uint4*)(hnq + (size_t)s * HID + r * 16);
#pragma unroll
                for (int q = 0; q < 4; ++q) {
                    unsigned int word = (q == 0) ? w.x : (q == 1) ? w.y : (q == 2) ? w.z : w.w;
                    acc[q * 4 + 0] += __builtin_amdgcn_cvt_f32_fp8((int)word, 0);
                    acc[q * 4 + 1] += __builtin_amdgcn_cvt_f32_fp8((int)word, 1);
                    acc[q * 4 + 2] += __builtin_amdgcn_cvt_f32_fp8((int)word, 2);
                    acc[q * 4 + 3] += __builtin_amdgcn_cvt_f32_fp8((int)word, 3);
                }
            }
        }
    }
    // reduce across g (masks 4,8,16,32)
#pragma unroll
    for (int k = 0; k < 16; ++k) {
        acc[k] += __shfl_xor(acc[k], 4, 64);
        acc[k] += __shfl_xor(acc[k], 8, 64);
        acc[k] += __shfl_xor(acc[k], 16, 64);
        acc[k] += __shfl_xor(acc[k], 32, 64);
    }
    float invdeg = 1.0f / fmaxf((float)(end - beg), 1.0f);
    const float* hsr = hs + (size_t)node * HID + r * 16;
    float v[16], ss = 0.f;
#pragma unroll
    for (int q = 0; q < 4; ++q) {
        f32x4 h4 = *(const f32x4*)(hsr + q * 4);
#pragma unroll
        for (int k = 0; k < 4; ++k) {
            float val = fmaxf(fmaf(acc[q * 4 + k], invdeg, h4[k]), 0.f);
            v[q * 4 + k] = val;
            ss += val * val;
        }
    }
    // reduce across r (masks 1,2): full 64-feature sum (g-groups duplicate)
    ss += __shfl_xor(ss, 1, 64);
    ss += __shfl_xor(ss, 2, 64);
    float rs = 1.0f / (sqrtf(ss) + EPS);
    if (MLP) {
        int wv = threadIdx.x >> 6;
        if (g == 0) {   // lanes 0..3 hold the 64 features (16 each), write fp32 row
#pragma unroll
            for (int k = 0; k < 16; ++k) sH[wv * HID + r * 16 + k] = v[k] * rs;
        }
        float p = 0.f;
        if (lane < 32) {
            float a2 = sB1[lane];
#pragma unroll
            for (int k = 0; k < HID; ++k) a2 = fmaf(sH[wv * HID + k], sW1[k * 32 + lane], a2);
            p = fmaxf(a2, 0.f) * sW2[lane];
        }
#pragma unroll
        for (int off = 32; off >= 1; off >>= 1) p += __shfl_xor(p, off, 64);
        if (lane == 0) out[node] = 1.0f / (1.0f + __expf(-(p + mb2[0])));
    } else {
        if (g == 0) {   // 4 lanes x 32B = full 128B bf16 row
            ushort8 o0, o1;
#pragma unroll
            for (int k = 0; k < 8; ++k) { o0[k] = f2bf(v[k] * rs); o1[k] = f2bf(v[k + 8] * rs); }
            *(ushort8*)(hb_out + (size_t)node * HID + r * 16)     = o0;
            *(ushort8*)(hb_out + (size_t)node * HID + r * 16 + 8) = o1;
        }
    }
}

extern "C" void kernel_launch(void* const* d_in, const int* in_sizes, int n_in,
                              void* d_out, int out_size, void* d_ws, size_t ws_size,
                              hipStream_t stream) {
    const float* x   = (const float*)d_in[0];
    const int*   ei  = (const int*)d_in[1];
    const float* w0s = (const float*)d_in[2];
    const float* w0n = (const float*)d_in[3];
    const float* w1s = (const float*)d_in[4];
    const float* w1n = (const float*)d_in[5];
    const float* w2s = (const float*)d_in[6];
    const float* w2n = (const float*)d_in[7];
    const float* mw1 = (const float*)d_in[8];
    const float* mb1 = (const float*)d_in[9];
    const float* mw2 = (const float*)d_in[10];
    const float* mb2 = (const float*)d_in[11];
    float*       out = (float*)d_out;

    // ---- workspace layout (all sections 16B aligned) ----
    int* rowptr      = (int*)d_ws;               // 50432 (>= N+1)
    int* csr_src     = rowptr + 50432;           // 1.6M
    int* blockCounts = csr_src + N_EDGES;        // NBLK*NB = 152881 (pad 153600)
    int* bucketBase  = blockCounts + 153600;     // 512
    int* totals      = bucketBase + 512;         // 512
    unsigned int* bucketPacked = (unsigned int*)(totals + 512);   // 1.6M uint (6.4MB)
    const size_t NH = (size_t)N_NODES * HID;
    float*          hs  = (float*)(bucketPacked + N_EDGES);       // NH f32
    unsigned char*  hnq = (unsigned char*)(hs + NH);              // NH fp8
    unsigned short* hb  = (unsigned short*)(hnq + NH);            // NH bf16
    unsigned short* p0S = hb + NH;               // 128*64
    unsigned short* p0N = p0S + IN_DIM * HID;
    unsigned short* p1S = p0N + IN_DIM * HID;    // 64*64
    unsigned short* p1N = p1S + HID * HID;
    unsigned short* p2S = p1N + HID * HID;
    unsigned short* p2N = p2S + HID * HID;
    // total ~36 MB

    const int nodeGrid = (N_NODES * HID) / 256;  // 12500 (covers nodes exactly)
    const int gemmGrid = (N_NODES / 16 + 3) / 4; // 782

    // ---- CSR build + weight pack + layer-0 GEMM (packed into idle dispatches) ----
    bucket_count_pack<<<NBLK + 8, 256, 0, stream>>>(
        ei, blockCounts, w0s, w0n, w1s, w1n, w2s, w2n,
        p0S, p0N, p1S, p1N, p2S, p2N);
    col_sum_gemm0<<<NB + gemmGrid, 256, 0, stream>>>(
        blockCounts, totals, x, p0S, p0N, hs, hnq);
    col_fix_base<<<NB, 256, 0, stream>>>(blockCounts, totals, bucketBase);
    bucket_scatter<<<NBLK, 256, 0, stream>>>(ei, blockCounts, bucketPacked);
    node_scan_scatter<<<NB, 256, 0, stream>>>(bucketPacked, bucketBase, rowptr, csr_src);

    // ---- layer 0 aggregate (gemm L0 already done in col_sum dispatch) ----
    agg_update<false><<<nodeGrid, 256, 0, stream>>>(
        rowptr, csr_src, hnq, hs, hb, nullptr, nullptr, nullptr, nullptr, nullptr);

    // ---- layer 1 ----
    gemm_dual_mfma<HID, false><<<gemmGrid, 256, 0, stream>>>(hb, p1S, p1N, hs, hnq);
    agg_update<false><<<nodeGrid, 256, 0, stream>>>(
        rowptr, csr_src, hnq, hs, hb, nullptr, nullptr, nullptr, nullptr, nullptr);

    // ---- layer 2 (+ fused MLP head) ----
    gemm_dual_mfma<HID, false><<<gemmGrid, 256, 0, stream>>>(hb, p2S, p2N, hs, hnq);
    agg_update<true><<<nodeGrid, 256, 0, stream>>>(
        rowptr, csr_src, hnq, hs, nullptr, mw1, mb1, mw2, mb2, out);
}

// Round 10
// 271.897 us; speedup vs baseline: 1.1432x; 1.1432x over previous
//
#include <hip/hip_runtime.h>
#include <hip/hip_bf16.h>
#include <math.h>

#define N_NODES 50000
#define N_EDGES 1600000
#define IN_DIM  128
#define HID     64
#define EPB     4096   // edges per sort block
#define NBLK    391    // ceil(N_EDGES / EPB)
#define NB      391    // ceil(N_NODES / 128) buckets of 128 nodes
#define CAP     8192   // LDS staging capacity (edges/bucket; mean 4092)
static constexpr float EPS = 1e-6f;

typedef __attribute__((ext_vector_type(8))) short          short8;   // 8 bf16
typedef __attribute__((ext_vector_type(8))) unsigned short ushort8;
typedef __attribute__((ext_vector_type(4))) float          f32x4;
typedef __attribute__((ext_vector_type(2))) float          f32x2;

__device__ __forceinline__ float bf2f(unsigned int hi_bits) {   // bits already in [31:16]
    union { unsigned int i; float f; } c; c.i = hi_bits; return c.f;
}
__device__ __forceinline__ unsigned short f2bf(float f) {   // round-nearest-even
    union { float f; unsigned int i; } c; c.f = f;
    unsigned int r = c.i + 0x7FFFu + ((c.i >> 16) & 1u);
    return (unsigned short)(r >> 16);
}
__device__ __forceinline__ unsigned char f2fp8(float f) {   // OCP e4m3, HW cvt
    int p = __builtin_amdgcn_cvt_pk_fp8_f32(f, f, 0, false);
    return (unsigned char)(p & 0xff);
}

// ==== weight packing =========================================================

template <int K>
__device__ __forceinline__ void pack_body(const float* __restrict__ wS,
                                          const float* __restrict__ wN,
                                          unsigned short* __restrict__ pS,
                                          unsigned short* __restrict__ pN, int blk) {
    constexpr int NSLOT = (K / 32) * 4 * 64;
    int slot = blk * 256 + (int)threadIdx.x;
    if (slot >= NSLOT) return;
    int lane = slot & 63;
    int ct   = slot >> 6;
    int t    = ct & 3;
    int c    = ct >> 2;
    int m    = lane & 15;
    int quad = lane >> 4;
    int col  = t * 16 + m;
#pragma unroll
    for (int j = 0; j < 8; ++j) {
        int k = c * 32 + quad * 8 + j;
        pS[slot * 8 + j] = f2bf(wS[k * 64 + col]);
        pN[slot * 8 + j] = f2bf(wN[k * 64 + col]);
    }
}

// ==== CSR build: binned counting sort ========================================

// blocks 0..NBLK-1: per-block bucket histogram; blocks NBLK..NBLK+7: weight pack
__global__ __launch_bounds__(256) void bucket_count_pack(
    const int* __restrict__ ei, int* __restrict__ blockCounts,
    const float* __restrict__ w0s, const float* __restrict__ w0n,
    const float* __restrict__ w1s, const float* __restrict__ w1n,
    const float* __restrict__ w2s, const float* __restrict__ w2n,
    unsigned short* __restrict__ p0S, unsigned short* __restrict__ p0N,
    unsigned short* __restrict__ p1S, unsigned short* __restrict__ p1N,
    unsigned short* __restrict__ p2S, unsigned short* __restrict__ p2N) {
    if (blockIdx.x >= NBLK) {
        int blk = blockIdx.x - NBLK;
        if (blk < 4)      pack_body<IN_DIM>(w0s, w0n, p0S, p0N, blk);
        else if (blk < 6) pack_body<HID>(w1s, w1n, p1S, p1N, blk - 4);
        else              pack_body<HID>(w2s, w2n, p2S, p2N, blk - 6);
        return;
    }
    __shared__ int hist[NB];
    for (int i = threadIdx.x; i < NB; i += 256) hist[i] = 0;
    __syncthreads();
    int base = blockIdx.x * EPB;
    int lim  = min(EPB, N_EDGES - base);
    for (int i = threadIdx.x; i < lim; i += 256)
        atomicAdd(&hist[ei[N_EDGES + base + i] >> 7], 1);
    __syncthreads();
    for (int b = threadIdx.x; b < NB; b += 256)
        blockCounts[blockIdx.x * NB + b] = hist[b];
}

// ==== dual GEMM body =========================================================
// hs = A@wS (fp32 out), hn = A@wN (fp8 e4m3 out)
template <int K, bool F32IN>
__device__ __forceinline__ void gemm_body(
    const void* __restrict__ Av,
    const unsigned short* __restrict__ pS,
    const unsigned short* __restrict__ pN,
    float* __restrict__ hs, unsigned char* __restrict__ hnq, int blk) {
    constexpr int NC = K / 32;
    int lane = threadIdx.x & 63;
    int wv   = threadIdx.x >> 6;
    int tile = blk * 4 + wv;
    if (tile >= N_NODES / 16) return;
    int m    = lane & 15;
    int quad = lane >> 4;

    const short8* pSf = (const short8*)pS;
    const short8* pNf = (const short8*)pN;

    f32x4 accS[4], accN[4];
#pragma unroll
    for (int t = 0; t < 4; ++t) {
        accS[t] = (f32x4){0.f, 0.f, 0.f, 0.f};
        accN[t] = (f32x4){0.f, 0.f, 0.f, 0.f};
    }
#pragma unroll
    for (int c = 0; c < NC; ++c) {
        short8 a;
        if constexpr (F32IN) {
            const float* Af = (const float*)Av + ((size_t)tile * 16 + m) * K + quad * 8 + c * 32;
            f32x4 a0 = *(const f32x4*)Af;
            f32x4 a1 = *(const f32x4*)(Af + 4);
#pragma unroll
            for (int k = 0; k < 4; ++k) a[k]     = (short)f2bf(a0[k]);
#pragma unroll
            for (int k = 0; k < 4; ++k) a[k + 4] = (short)f2bf(a1[k]);
        } else {
            const short8* Af = (const short8*)((const unsigned short*)Av +
                               ((size_t)tile * 16 + m) * K + quad * 8);
            a = Af[c * 4];
        }
#pragma unroll
        for (int t = 0; t < 4; ++t) {
            short8 bs = pSf[(c * 4 + t) * 64 + lane];
            short8 bn = pNf[(c * 4 + t) * 64 + lane];
            accS[t] = __builtin_amdgcn_mfma_f32_16x16x32_bf16(a, bs, accS[t], 0, 0, 0);
            accN[t] = __builtin_amdgcn_mfma_f32_16x16x32_bf16(a, bn, accN[t], 0, 0, 0);
        }
    }
    int row0 = tile * 16 + quad * 4;
#pragma unroll
    for (int t = 0; t < 4; ++t) {
#pragma unroll
        for (int r = 0; r < 4; ++r) {
            size_t o = (size_t)(row0 + r) * HID + t * 16 + m;
            hs[o]  = accS[t][r];
            hnq[o] = f2fp8(accN[t][r]);
        }
    }
}

// blocks 0..NB-1: col_sum; blocks NB.. : layer-0 GEMM (independent work overlap)
__global__ __launch_bounds__(256) void col_sum_gemm0(
    const int* __restrict__ blockCounts, int* __restrict__ totals,
    const float* __restrict__ x,
    const unsigned short* __restrict__ p0S, const unsigned short* __restrict__ p0N,
    float* __restrict__ hs, unsigned char* __restrict__ hnq) {
    if (blockIdx.x >= NB) {
        gemm_body<IN_DIM, true>(x, p0S, p0N, hs, hnq, blockIdx.x - NB);
        return;
    }
    __shared__ int ws[4];
    int b = blockIdx.x;
    int s = 0;
    for (int i = threadIdx.x; i < NBLK; i += 256) s += blockCounts[i * NB + b];
#pragma unroll
    for (int off = 32; off >= 1; off >>= 1) s += __shfl_xor(s, off, 64);
    if ((threadIdx.x & 63) == 0) ws[threadIdx.x >> 6] = s;
    __syncthreads();
    if (threadIdx.x == 0) totals[b] = ws[0] + ws[1] + ws[2] + ws[3];
}

// col_fix + integrated base scan
__global__ __launch_bounds__(256) void col_fix_base(int* __restrict__ blockCounts,
                                                    const int* __restrict__ totals,
                                                    int* __restrict__ bucketBase) {
    __shared__ int vals[NBLK];
    __shared__ int sbase;
    int b = blockIdx.x;
    for (int i = threadIdx.x; i < NBLK; i += 256) vals[i] = blockCounts[i * NB + b];
    if (threadIdx.x < 64) {   // wave 0: base_b = sum totals[0..b)
        int lane = threadIdx.x;
        int s = 0;
        for (int i = lane; i < b; i += 64) s += totals[i];
#pragma unroll
        for (int off = 32; off >= 1; off >>= 1) s += __shfl_xor(s, off, 64);
        if (lane == 0) {
            sbase = s;
            bucketBase[b] = s;
            if (b == NB - 1) bucketBase[NB] = s + totals[b];   // == N_EDGES
        }
    }
    __syncthreads();
    if (threadIdx.x < 64) {
        int lane  = threadIdx.x;
        int carry = sbase;
        for (int base = 0; base < NBLK; base += 64) {
            int i = base + lane;
            int v = (i < NBLK) ? vals[i] : 0;
            int incl = v;
#pragma unroll
            for (int off = 1; off < 64; off <<= 1) {
                int t = __shfl_up(incl, off, 64);
                if (lane >= off) incl += t;
            }
            if (i < NBLK) vals[i] = carry + incl - v;
            carry += __shfl(incl, 63, 64);
        }
    }
    __syncthreads();
    for (int i = threadIdx.x; i < NBLK; i += 256) blockCounts[i * NB + b] = vals[i];
}

// scatter edges into bucket-sorted order, packed (src<<7)|(dst&127)
__global__ __launch_bounds__(256) void bucket_scatter(const int* __restrict__ ei,
                                                      const int* __restrict__ blockCounts,
                                                      unsigned int* __restrict__ bucketPacked) {
    __shared__ int cur[NB];
    for (int b = threadIdx.x; b < NB; b += 256)
        cur[b] = blockCounts[blockIdx.x * NB + b];
    __syncthreads();
    int base = blockIdx.x * EPB;
    int lim  = min(EPB, N_EDGES - base);
    for (int i = threadIdx.x; i < lim; i += 256) {
        int s = ei[base + i];
        int d = ei[N_EDGES + base + i];
        int pos = atomicAdd(&cur[d >> 7], 1);
        bucketPacked[pos] = ((unsigned int)s << 7) | (unsigned int)(d & 127);
    }
}

// fused: per-bucket degree count -> in-bucket scan -> rowptr -> local scatter.
__global__ __launch_bounds__(256) void node_scan_scatter(
    const unsigned int* __restrict__ bucketPacked, const int* __restrict__ bucketBase,
    int* __restrict__ rowptr, int* __restrict__ csr_src) {
    __shared__ int cnt[128];
    __shared__ int half0;
    __shared__ unsigned int stage[CAP];
    int tid = threadIdx.x;
    if (tid < 128) cnt[tid] = 0;
    __syncthreads();
    int beg = bucketBase[blockIdx.x], end = bucketBase[blockIdx.x + 1];
    int n = end - beg;
    for (int i = tid; i < n; i += 256) {
        unsigned int e = bucketPacked[beg + i];
        if (i < CAP) stage[i] = e;
        atomicAdd(&cnt[e & 127], 1);
    }
    __syncthreads();
    int lane = tid & 63;
    int v    = (tid < 128) ? cnt[tid] : 0;
    int incl = v;
#pragma unroll
    for (int off = 1; off < 64; off <<= 1) {
        int t = __shfl_up(incl, off, 64);
        if (lane >= off) incl += t;
    }
    if (tid == 63) half0 = incl;
    __syncthreads();
    int base  = beg + ((tid >= 64 && tid < 128) ? half0 : 0);
    int start = base + incl - v;
    int node  = blockIdx.x * 128 + tid;
    if (tid < 128) {
        if (node < N_NODES) rowptr[node] = start;
        cnt[tid] = start;   // becomes the scatter cursor
    }
    if (blockIdx.x == 0 && tid == 128) rowptr[N_NODES] = N_EDGES;
    __syncthreads();
    for (int i = tid; i < n; i += 256) {
        unsigned int e = (i < CAP) ? stage[i] : bucketPacked[beg + i];
        int pos = atomicAdd(&cnt[e & 127], 1);
        csr_src[pos] = (int)(e >> 7);
    }
}

// ==== gemm wrapper (layers 1,2) ==============================================
template <int K, bool F32IN>
__global__ __launch_bounds__(256) void gemm_dual_mfma(
    const void* __restrict__ Av,
    const unsigned short* __restrict__ pS,
    const unsigned short* __restrict__ pN,
    float* __restrict__ hs, unsigned char* __restrict__ hnq) {
    gemm_body<K, F32IN>(Av, pS, pN, hs, hnq, blockIdx.x);
}

// ==== fused gather-aggregate + update (+ optional MLP head) ==================
// Round-8 shape: g = lane>>3 (8 edge slots), r = lane&7 (8B chunk of the 64B
// fp8 row). Packed fp8->f32 converts + float2 accumulate halve VALU issue.
template <bool MLP>
__global__ __launch_bounds__(256) void agg_update(
    const int* __restrict__ rowptr, const int* __restrict__ csr_src,
    const unsigned char* __restrict__ hnq, const float* __restrict__ hs,
    unsigned short* __restrict__ hb_out,
    const float* __restrict__ mw1, const float* __restrict__ mb1,
    const float* __restrict__ mw2, const float* __restrict__ mb2,
    float* __restrict__ out) {
    __shared__ float sW1[MLP ? HID * 32 : 1];
    __shared__ float sW2[MLP ? 32 : 1];
    __shared__ float sB1[MLP ? 32 : 1];
    __shared__ float sH[MLP ? 4 * HID : 1];
    if (MLP) {
        for (int i = threadIdx.x; i < HID * 32; i += 256) sW1[i] = mw1[i];
        if (threadIdx.x < 32) { sW2[threadIdx.x] = mw2[threadIdx.x]; sB1[threadIdx.x] = mb1[threadIdx.x]; }
        __syncthreads();
    }
    int node = (blockIdx.x * 256 + threadIdx.x) >> 6;   // grid covers exactly N_NODES
    int lane = threadIdx.x & 63;
    int g = lane >> 3;   // edge slot 0..7
    int r = lane & 7;    // 8B chunk 0..7
    int beg = rowptr[node];
    int end = rowptr[node + 1];
    f32x2 acc2[4];
#pragma unroll
    for (int k = 0; k < 4; ++k) acc2[k] = (f32x2){0.f, 0.f};
    for (int e = beg; e < end; e += 64) {
        int cnt = min(64, end - e);
        int idx = (lane < cnt) ? csr_src[e + lane] : 0;
        for (int j = 0; j < cnt; j += 8) {
            int s = __shfl(idx, j + g, 64);
            if (j + g < cnt) {
                uint2 w = *(const uint2*)(hnq + (size_t)s * HID + r * 8);
#if __has_builtin(__builtin_amdgcn_cvt_pk_f32_fp8)
                acc2[0] += __builtin_amdgcn_cvt_pk_f32_fp8((int)w.x, false);
                acc2[1] += __builtin_amdgcn_cvt_pk_f32_fp8((int)w.x, true);
                acc2[2] += __builtin_amdgcn_cvt_pk_f32_fp8((int)w.y, false);
                acc2[3] += __builtin_amdgcn_cvt_pk_f32_fp8((int)w.y, true);
#else
                acc2[0] += (f32x2){__builtin_amdgcn_cvt_f32_fp8((int)w.x, 0),
                                   __builtin_amdgcn_cvt_f32_fp8((int)w.x, 1)};
                acc2[1] += (f32x2){__builtin_amdgcn_cvt_f32_fp8((int)w.x, 2),
                                   __builtin_amdgcn_cvt_f32_fp8((int)w.x, 3)};
                acc2[2] += (f32x2){__builtin_amdgcn_cvt_f32_fp8((int)w.y, 0),
                                   __builtin_amdgcn_cvt_f32_fp8((int)w.y, 1)};
                acc2[3] += (f32x2){__builtin_amdgcn_cvt_f32_fp8((int)w.y, 2),
                                   __builtin_amdgcn_cvt_f32_fp8((int)w.y, 3)};
#endif
            }
        }
    }
    float acc[8];
#pragma unroll
    for (int k = 0; k < 4; ++k) { acc[2 * k] = acc2[k][0]; acc[2 * k + 1] = acc2[k][1]; }
    // reduce across g (masks 8,16,32)
#pragma unroll
    for (int k = 0; k < 8; ++k) {
        acc[k] += __shfl_xor(acc[k], 8, 64);
        acc[k] += __shfl_xor(acc[k], 16, 64);
        acc[k] += __shfl_xor(acc[k], 32, 64);
    }
    float invdeg = 1.0f / fmaxf((float)(end - beg), 1.0f);
    const float* hsr = hs + (size_t)node * HID + r * 8;
    f32x4 h0 = *(const f32x4*)hsr;
    f32x4 h1 = *(const f32x4*)(hsr + 4);
    float v[8], ss = 0.f;
#pragma unroll
    for (int k = 0; k < 8; ++k) {
        float hk = (k < 4) ? h0[k] : h1[k - 4];
        v[k] = fmaxf(fmaf(acc[k], invdeg, hk), 0.f);
        ss += v[k] * v[k];
    }
    // reduce across r (masks 1,2,4): full 64-feature sum (g-groups duplicate)
    ss += __shfl_xor(ss, 1, 64);
    ss += __shfl_xor(ss, 2, 64);
    ss += __shfl_xor(ss, 4, 64);
    float rs = 1.0f / (sqrtf(ss) + EPS);
    if (MLP) {
        int wv = threadIdx.x >> 6;
        if (g == 0) {   // lanes 0..7 hold the 64 features (8 each), stage fp32 row
#pragma unroll
            for (int k = 0; k < 8; ++k) sH[wv * HID + r * 8 + k] = v[k] * rs;
        }
        float p = 0.f;
        if (lane < 32) {
            float a2 = sB1[lane];
#pragma unroll
            for (int k = 0; k < HID; ++k) a2 = fmaf(sH[wv * HID + k], sW1[k * 32 + lane], a2);
            p = fmaxf(a2, 0.f) * sW2[lane];
        }
#pragma unroll
        for (int off = 32; off >= 1; off >>= 1) p += __shfl_xor(p, off, 64);
        if (lane == 0) out[node] = 1.0f / (1.0f + __expf(-(p + mb2[0])));
    } else {
        if (g == 0) {   // 8 lanes x 16B = full 128B bf16 row
            ushort8 o;
#pragma unroll
            for (int k = 0; k < 8; ++k) o[k] = f2bf(v[k] * rs);
            *(ushort8*)(hb_out + (size_t)node * HID + r * 8) = o;
        }
    }
}

extern "C" void kernel_launch(void* const* d_in, const int* in_sizes, int n_in,
                              void* d_out, int out_size, void* d_ws, size_t ws_size,
                              hipStream_t stream) {
    const float* x   = (const float*)d_in[0];
    const int*   ei  = (const int*)d_in[1];
    const float* w0s = (const float*)d_in[2];
    const float* w0n = (const float*)d_in[3];
    const float* w1s = (const float*)d_in[4];
    const float* w1n = (const float*)d_in[5];
    const float* w2s = (const float*)d_in[6];
    const float* w2n = (const float*)d_in[7];
    const float* mw1 = (const float*)d_in[8];
    const float* mb1 = (const float*)d_in[9];
    const float* mw2 = (const float*)d_in[10];
    const float* mb2 = (const float*)d_in[11];
    float*       out = (float*)d_out;

    // ---- workspace layout (all sections 16B aligned) ----
    int* rowptr      = (int*)d_ws;               // 50432 (>= N+1)
    int* csr_src     = rowptr + 50432;           // 1.6M
    int* blockCounts = csr_src + N_EDGES;        // NBLK*NB = 152881 (pad 153600)
    int* bucketBase  = blockCounts + 153600;     // 512
    int* totals      = bucketBase + 512;         // 512
    unsigned int* bucketPacked = (unsigned int*)(totals + 512);   // 1.6M uint (6.4MB)
    const size_t NH = (size_t)N_NODES * HID;
    float*          hs  = (float*)(bucketPacked + N_EDGES);       // NH f32
    unsigned char*  hnq = (unsigned char*)(hs + NH);              // NH fp8
    unsigned short* hb  = (unsigned short*)(hnq + NH);            // NH bf16
    unsigned short* p0S = hb + NH;               // 128*64
    unsigned short* p0N = p0S + IN_DIM * HID;
    unsigned short* p1S = p0N + IN_DIM * HID;    // 64*64
    unsigned short* p1N = p1S + HID * HID;
    unsigned short* p2S = p1N + HID * HID;
    unsigned short* p2N = p2S + HID * HID;
    // total ~36 MB

    const int nodeGrid = (N_NODES * HID) / 256;  // 12500 (covers nodes exactly)
    const int gemmGrid = (N_NODES / 16 + 3) / 4; // 782

    // ---- CSR build + weight pack + layer-0 GEMM (packed into idle dispatches) ----
    bucket_count_pack<<<NBLK + 8, 256, 0, stream>>>(
        ei, blockCounts, w0s, w0n, w1s, w1n, w2s, w2n,
        p0S, p0N, p1S, p1N, p2S, p2N);
    col_sum_gemm0<<<NB + gemmGrid, 256, 0, stream>>>(
        blockCounts, totals, x, p0S, p0N, hs, hnq);
    col_fix_base<<<NB, 256, 0, stream>>>(blockCounts, totals, bucketBase);
    bucket_scatter<<<NBLK, 256, 0, stream>>>(ei, blockCounts, bucketPacked);
    node_scan_scatter<<<NB, 256, 0, stream>>>(bucketPacked, bucketBase, rowptr, csr_src);

    // ---- layer 0 aggregate (gemm L0 already done in col_sum dispatch) ----
    agg_update<false><<<nodeGrid, 256, 0, stream>>>(
        rowptr, csr_src, hnq, hs, hb, nullptr, nullptr, nullptr, nullptr, nullptr);

    // ---- layer 1 ----
    gemm_dual_mfma<HID, false><<<gemmGrid, 256, 0, stream>>>(hb, p1S, p1N, hs, hnq);
    agg_update<false><<<nodeGrid, 256, 0, stream>>>(
        rowptr, csr_src, hnq, hs, hb, nullptr, nullptr, nullptr, nullptr, nullptr);

    // ---- layer 2 (+ fused MLP head) ----
    gemm_dual_mfma<HID, false><<<gemmGrid, 256, 0, stream>>>(hb, p2S, p2N, hs, hnq);
    agg_update<true><<<nodeGrid, 256, 0, stream>>>(
        rowptr, csr_src, hnq, hs, nullptr, mw1, mb1, mw2, mb2, out);
}